// Round 8
// baseline (504.332 us; speedup 1.0000x reference)
//
#include <hip/hip_runtime.h>

#define N_NODES 200000
#define N_EDGES 6400000
#define K_BUCKETS 256
#define BUCKET 784          // 256*784 = 200704 >= 200000; dl < 1024
#define NSB 3200            // chunks
#define CHUNK 2000          // NSB*CHUNK == N_EDGES exactly
#define P_SPLIT 8           // blocks per bucket in aggregation

__device__ __forceinline__ unsigned short f2bf(float x) {
    unsigned u = __float_as_uint(x);
    u += 0x7fffu + ((u >> 16) & 1u);      // RNE to bf16
    return (unsigned short)(u >> 16);
}
__device__ __forceinline__ float bf2f(unsigned short h) {
    return __uint_as_float((unsigned)h << 16);
}

// non-temporal helpers (bypass L2 allocation for read/write-once streams)
__device__ __forceinline__ int   ntl(const int* p)            { return __builtin_nontemporal_load(p); }
__device__ __forceinline__ unsigned ntl(const unsigned* p)    { return __builtin_nontemporal_load(p); }
__device__ __forceinline__ float ntl(const float* p)          { return __builtin_nontemporal_load(p); }
__device__ __forceinline__ unsigned short ntl(const unsigned short* p) { return __builtin_nontemporal_load(p); }
__device__ __forceinline__ void nts(int* p, int v)            { __builtin_nontemporal_store(v, p); }
__device__ __forceinline__ void nts(unsigned* p, unsigned v)  { __builtin_nontemporal_store(v, p); }
__device__ __forceinline__ void nts(float* p, float v)        { __builtin_nontemporal_store(v, p); }
__device__ __forceinline__ void nts(unsigned short* p, unsigned short v) { __builtin_nontemporal_store(v, p); }

// ---------------- fast path ----------------

// x_out = z0 ; u0 = a0.z0 ; v0 = q0.z0   (S0 = 0)
__global__ __launch_bounds__(256) void prep_kernel(
    const float4* __restrict__ z, float4* __restrict__ x_out,
    const float* __restrict__ W,
    float* __restrict__ u, float* __restrict__ v)
{
    int n = blockIdx.x * 256 + threadIdx.x;
    if (n >= N_NODES) return;
    float4 zv = z[n];
    x_out[n] = zv;
    float a0 = W[0], a1 = W[1], a2 = W[2], a3 = W[3];
    float q0 = W[4], q1 = W[5], q2 = W[6], q3 = W[7];
    u[n] = a0 * zv.x + a1 * zv.y + a2 * zv.z + a3 * zv.w;
    v[n] = q0 * zv.x + q1 * zv.y + q2 * zv.z + q3 * zv.w;
}

// per-chunk bucket histogram, layout counts[sb*K + k]  (coalesced store)
__global__ __launch_bounds__(256) void hist_kernel(const int* __restrict__ dst,
                                                   int* __restrict__ counts)
{
    __shared__ int cnt[K_BUCKETS];
    int tid = threadIdx.x, sb = blockIdx.x;
    cnt[tid] = 0;
    __syncthreads();
    int e0 = sb * CHUNK;
    for (int i = tid; i < CHUNK; i += 256)
        atomicAdd(&cnt[ntl(dst + e0 + i) / BUCKET], 1);
    __syncthreads();
    counts[sb * K_BUCKETS + tid] = cnt[tid];
}

// per-bucket exclusive scan across chunks
__global__ __launch_bounds__(256) void scan_cols(const int* __restrict__ counts,
                                                 int* __restrict__ baseRel,
                                                 int* __restrict__ tot)
{
    __shared__ int buf[256];
    __shared__ int carry_s;
    int k = blockIdx.x, tid = threadIdx.x;
    if (tid == 0) carry_s = 0;
    __syncthreads();
    for (int base = 0; base < NSB; base += 256) {
        int idx = base + tid;
        int v = (idx < NSB) ? counts[idx * K_BUCKETS + k] : 0;
        buf[tid] = v;
        __syncthreads();
        for (int off = 1; off < 256; off <<= 1) {
            int t = (tid >= off) ? buf[tid - off] : 0;
            __syncthreads();
            buf[tid] += t;
            __syncthreads();
        }
        int incl = buf[tid];
        if (idx < NSB) baseRel[idx * K_BUCKETS + k] = carry_s + incl - v;
        __syncthreads();
        if (tid == 255) carry_s += incl;
        __syncthreads();
    }
    if (tid == 255) tot[k] = carry_s;
}

__global__ __launch_bounds__(256) void scan_tot(const int* __restrict__ tot,
                                                int* __restrict__ bstart)
{
    __shared__ int buf[256];
    int tid = threadIdx.x;
    int v = tot[tid];
    buf[tid] = v;
    __syncthreads();
    for (int off = 1; off < 256; off <<= 1) {
        int t = (tid >= off) ? buf[tid - off] : 0;
        __syncthreads();
        buf[tid] += t;
        __syncthreads();
    }
    bstart[tid] = buf[tid] - v;
    if (tid == 255) bstart[256] = buf[255];
}

// counting-sort scatter: counts pre-loaded; permutation in LDS; nt streams
__global__ __launch_bounds__(256) void scatter_kernel(
    const int* __restrict__ src, const int* __restrict__ dst,
    const float* __restrict__ r, const float* __restrict__ r_hat,
    const float* __restrict__ W, const float* __restrict__ b,
    const int* __restrict__ counts, const int* __restrict__ baseRel,
    const int* __restrict__ bstart,
    int* __restrict__ packedA, unsigned* __restrict__ c01a,
    unsigned short* __restrict__ c2a)
{
    __shared__ int cur[K_BUCKETS];
    __shared__ int delta[K_BUCKETS];
    __shared__ int scanbuf[256];
    __shared__ int            lpack[CHUNK];
    __shared__ unsigned       lc01[CHUNK];
    __shared__ unsigned short lc2[CHUNK];
    __shared__ unsigned char  skb[CHUNK];

    int tid = threadIdx.x, sb = blockIdx.x;

    int v = counts[sb * K_BUCKETS + tid];
    scanbuf[tid] = v;
    __syncthreads();
    for (int off = 1; off < 256; off <<= 1) {
        int t = (tid >= off) ? scanbuf[tid - off] : 0;
        __syncthreads();
        scanbuf[tid] += t;
        __syncthreads();
    }
    int localBase = scanbuf[tid] - v;
    int gBase = bstart[tid] + baseRel[sb * K_BUCKETS + tid];
    delta[tid] = gBase - localBase;
    cur[tid] = localBase;
    __syncthreads();

    float w8_0 = W[8],  w9_0 = W[9],  w10_0 = W[10], w11_0 = W[11], b0 = b[0];
    float w8_1 = W[20], w9_1 = W[21], w10_1 = W[22], w11_1 = W[23], b1 = b[1];
    float w8_2 = W[32], w9_2 = W[33], w10_2 = W[34], w11_2 = W[35], b2 = b[2];

    int e0 = sb * CHUNK;
    // pass B: coalesced nt global reads, scattered LDS writes to sorted slot
    for (int i = tid; i < CHUNK; i += 256) {
        int e = e0 + i;
        int d = ntl(dst + e);
        int k = d / BUCKET;
        int dl = d - k * BUCKET;
        int slot = atomicAdd(&cur[k], 1);
        int sn = ntl(src + e);
        float rv = ntl(r + e);
        size_t he = 3 * (size_t)e;
        float h0 = ntl(r_hat + he), h1 = ntl(r_hat + he + 1), h2 = ntl(r_hat + he + 2);
        lpack[slot] = (sn << 10) | dl;
        unsigned cc0 = f2bf(w8_0 * rv + w9_0 * h0 + w10_0 * h1 + w11_0 * h2 + b0);
        unsigned cc1 = f2bf(w8_1 * rv + w9_1 * h0 + w10_1 * h1 + w11_1 * h2 + b1);
        lc01[slot] = cc0 | (cc1 << 16);
        lc2[slot]  = f2bf(w8_2 * rv + w9_2 * h0 + w10_2 * h1 + w11_2 * h2 + b2);
        skb[slot]  = (unsigned char)k;
    }
    __syncthreads();

    // pass C: sequential LDS reads, coalesced nt global stores
    for (int s = tid; s < CHUNK; s += 256) {
        int k = skb[s];
        int gpos = delta[k] + s;
        nts(packedA + gpos, lpack[s]);
        nts(c01a + gpos, lc01[s]);
        nts(c2a + gpos, lc2[s]);
    }
}

// partial aggregation: P_SPLIT blocks per bucket; nt streams so u stays in L2
template<int LAYER>
__global__ __launch_bounds__(256) void pagg_kernel(
    const int* __restrict__ packedA, const unsigned* __restrict__ c01a,
    const unsigned short* __restrict__ c2a, const int* __restrict__ bstart,
    const float* __restrict__ u, const float* __restrict__ v,
    float* __restrict__ partial)
{
    __shared__ float vsl[BUCKET];
    __shared__ float aggsl[BUCKET];
    int tid = threadIdx.x, blk = blockIdx.x;
    int k = blk / P_SPLIT;
    int p = blk - k * P_SPLIT;
    int nbase = k * BUCKET;
    int nn = min(BUCKET, N_NODES - nbase);

    for (int i = tid; i < BUCKET; i += 256) {
        aggsl[i] = 0.0f;
        vsl[i] = (i < nn) ? v[nbase + i] : 0.0f;
    }
    __syncthreads();

    int estart = bstart[k], eend = bstart[k + 1];
    int len = eend - estart;
    int per = (len + P_SPLIT - 1) / P_SPLIT;
    int lo = estart + p * per;
    int hi = min(lo + per, eend);

    for (int j = lo + tid; j < hi; j += 256) {
        int pack = ntl(packedA + j);
        int s = pack >> 10;
        int dl = pack & 1023;
        float c;
        if (LAYER == 2) c = bf2f(ntl(c2a + j));
        else            c = bf2f((unsigned short)(ntl(c01a + j) >> (16 * LAYER)));
        atomicAdd(&aggsl[dl], u[s] + vsl[dl] + c);       // ds_add_f32; u[] L2-hot
    }
    __syncthreads();

    float* pout = partial + (size_t)blk * BUCKET;
    for (int i = tid; i < BUCKET; i += 256) nts(pout + i, aggsl[i]);
}

// finalize layer: S' = S + sum(partials); compute next u,v (or final z)
__global__ __launch_bounds__(256) void fin_kernel(
    const float4* __restrict__ z0, const float* __restrict__ partial,
    const float* __restrict__ Sin, float* __restrict__ Sout,
    const float* __restrict__ W, int layer,
    float* __restrict__ u, float* __restrict__ v, float4* __restrict__ z_out)
{
    int n = blockIdx.x * 256 + threadIdx.x;
    if (n >= N_NODES) return;
    int k = n / BUCKET;
    int i = n - k * BUCKET;
    float agg = 0.0f;
    const float* pk = partial + (size_t)k * P_SPLIT * BUCKET + i;
#pragma unroll
    for (int p = 0; p < P_SPLIT; ++p) agg += ntl(pk + (size_t)p * BUCKET);
    float S = ((layer == 0) ? 0.0f : Sin[n]) + agg;
    if (layer < 2) {
        const float* Wn = W + 12 * (layer + 1);
        float a0 = Wn[0], a1 = Wn[1], a2 = Wn[2], a3 = Wn[3];
        float q0 = Wn[4], q1 = Wn[5], q2 = Wn[6], q3 = Wn[7];
        float A = a0 + a1 + a2 + a3, B = q0 + q1 + q2 + q3;
        float4 zv = z0[n];
        Sout[n] = S;
        u[n] = a0 * zv.x + a1 * zv.y + a2 * zv.z + a3 * zv.w + A * S;
        v[n] = q0 * zv.x + q1 * zv.y + q2 * zv.z + q3 * zv.w + B * S;
    } else {
        float4 zv = z0[n];
        zv.x += S; zv.y += S; zv.z += S; zv.w += S;
        z_out[n] = zv;
    }
}

// ---------------- fallback (round-2) ----------------

__global__ __launch_bounds__(256) void init_kernel(
    const float4* __restrict__ z_in, float4* __restrict__ z_cur,
    float4* __restrict__ x_out, float* __restrict__ agg)
{
    int n = blockIdx.x * blockDim.x + threadIdx.x;
    if (n < N_NODES) {
        float4 vv = z_in[n];
        z_cur[n] = vv; x_out[n] = vv; agg[n] = 0.0f;
    }
}

__global__ __launch_bounds__(256) void edge_kernel(
    const float* __restrict__ z, const float* __restrict__ r,
    const float* __restrict__ r_hat, const int* __restrict__ src,
    const int* __restrict__ dst, const float* __restrict__ Wl,
    const float* __restrict__ bl, float* __restrict__ agg)
{
    int e = blockIdx.x * blockDim.x + threadIdx.x;
    if (e >= N_EDGES) return;
    float w0 = Wl[0], w1 = Wl[1], w2 = Wl[2], w3 = Wl[3];
    float w4 = Wl[4], w5 = Wl[5], w6 = Wl[6], w7 = Wl[7];
    float w8 = Wl[8], w9 = Wl[9], w10 = Wl[10], w11 = Wl[11];
    float bias = bl[0];
    int s = src[e], d = dst[e];
    float4 zs = ((const float4*)z)[s];
    float4 zd = ((const float4*)z)[d];
    float rv = r[e];
    const float* rh = r_hat + 3 * (size_t)e;
    float msg = w0*zs.x + w1*zs.y + w2*zs.z + w3*zs.w
              + w4*zd.x + w5*zd.y + w6*zd.z + w7*zd.w
              + w8*rv + w9*rh[0] + w10*rh[1] + w11*rh[2] + bias;
    unsafeAtomicAdd(&agg[d], msg);
}

__global__ __launch_bounds__(256) void node_update(float4* __restrict__ z_cur,
                                                   float* __restrict__ agg)
{
    int n = blockIdx.x * blockDim.x + threadIdx.x;
    if (n < N_NODES) {
        float a = agg[n]; float4 vv = z_cur[n];
        vv.x += a; vv.y += a; vv.z += a; vv.w += a;
        z_cur[n] = vv; agg[n] = 0.0f;
    }
}

__global__ __launch_bounds__(256) void final_update(const float4* __restrict__ z_cur,
                                                    const float* __restrict__ agg,
                                                    float4* __restrict__ z_out)
{
    int n = blockIdx.x * blockDim.x + threadIdx.x;
    if (n < N_NODES) {
        float a = agg[n]; float4 vv = z_cur[n];
        vv.x += a; vv.y += a; vv.z += a; vv.w += a;
        z_out[n] = vv;
    }
}

// ---------------- launch ----------------

extern "C" void kernel_launch(void* const* d_in, const int* in_sizes, int n_in,
                              void* d_out, int out_size, void* d_ws, size_t ws_size,
                              hipStream_t stream)
{
    const float* z     = (const float*)d_in[0];
    const float* r     = (const float*)d_in[1];
    const float* r_hat = (const float*)d_in[2];
    const float* W     = (const float*)d_in[3];
    const float* b     = (const float*)d_in[4];
    const int*   src   = (const int*)d_in[5];
    const int*   dst   = (const int*)d_in[6];
    float* out = (float*)d_out;

    char* ws = (char*)d_ws;
    size_t off = 0;
    auto alloc = [&](size_t bytes) {
        void* p = ws + off;
        off += (bytes + 15) & ~(size_t)15;
        return p;
    };
    int*            packedA = (int*)alloc((size_t)N_EDGES * 4);
    unsigned*       c01a    = (unsigned*)alloc((size_t)N_EDGES * 4);
    unsigned short* c2a     = (unsigned short*)alloc((size_t)N_EDGES * 2);
    int*            counts  = (int*)alloc((size_t)NSB * K_BUCKETS * 4);
    int*            baseRel = (int*)alloc((size_t)NSB * K_BUCKETS * 4);
    int*            tot     = (int*)alloc((size_t)K_BUCKETS * 4);
    int*            bstart  = (int*)alloc((size_t)(K_BUCKETS + 1) * 4);
    float*          Sa      = (float*)alloc((size_t)N_NODES * 4);
    float*          Sb      = (float*)alloc((size_t)N_NODES * 4);
    float*          ubuf    = (float*)alloc((size_t)N_NODES * 4);
    float*          vbuf    = (float*)alloc((size_t)N_NODES * 4);
    float*          partial = (float*)alloc((size_t)K_BUCKETS * P_SPLIT * BUCKET * 4);
    size_t required = off;

    dim3 nblk((N_NODES + 255) / 256);

    if (ws_size >= required) {
        prep_kernel<<<nblk, 256, 0, stream>>>(
            (const float4*)z, (float4*)(out + 4 * (size_t)N_NODES), W, ubuf, vbuf);
        hist_kernel<<<NSB, 256, 0, stream>>>(dst, counts);
        scan_cols<<<K_BUCKETS, 256, 0, stream>>>(counts, baseRel, tot);
        scan_tot<<<1, 256, 0, stream>>>(tot, bstart);
        scatter_kernel<<<NSB, 256, 0, stream>>>(src, dst, r, r_hat, W, b,
                                                counts, baseRel, bstart,
                                                packedA, c01a, c2a);
        // layer 0
        pagg_kernel<0><<<K_BUCKETS * P_SPLIT, 256, 0, stream>>>(
            packedA, c01a, c2a, bstart, ubuf, vbuf, partial);
        fin_kernel<<<nblk, 256, 0, stream>>>(
            (const float4*)z, partial, Sa, Sa, W, 0, ubuf, vbuf, (float4*)out);
        // layer 1
        pagg_kernel<1><<<K_BUCKETS * P_SPLIT, 256, 0, stream>>>(
            packedA, c01a, c2a, bstart, ubuf, vbuf, partial);
        fin_kernel<<<nblk, 256, 0, stream>>>(
            (const float4*)z, partial, Sa, Sb, W, 1, ubuf, vbuf, (float4*)out);
        // layer 2
        pagg_kernel<2><<<K_BUCKETS * P_SPLIT, 256, 0, stream>>>(
            packedA, c01a, c2a, bstart, ubuf, vbuf, partial);
        fin_kernel<<<nblk, 256, 0, stream>>>(
            (const float4*)z, partial, Sb, Sb, W, 2, ubuf, vbuf, (float4*)out);
    } else {
        // fallback: round-2 path
        float* agg   = (float*)d_ws;
        float* z_cur = agg + N_NODES;
        dim3 eblk((N_EDGES + 255) / 256);
        init_kernel<<<nblk, 256, 0, stream>>>(
            (const float4*)z, (float4*)z_cur,
            (float4*)(out + 4 * (size_t)N_NODES), agg);
        for (int i = 0; i < 3; ++i) {
            edge_kernel<<<eblk, 256, 0, stream>>>(
                z_cur, r, r_hat, src, dst, W + 12 * i, b + i, agg);
            if (i < 2)
                node_update<<<nblk, 256, 0, stream>>>((float4*)z_cur, agg);
            else
                final_update<<<nblk, 256, 0, stream>>>(
                    (const float4*)z_cur, agg, (float4*)out);
        }
    }
}

// Round 9
// 495.354 us; speedup vs baseline: 1.0181x; 1.0181x over previous
//
#include <hip/hip_runtime.h>

#define N_NODES 200000
#define N_EDGES 6400000
#define K_BUCKETS 256
#define BUCKET 784          // 256*784 = 200704 >= 200000; dl < 1024
#define NSB 3200            // chunks
#define CHUNK 2000          // NSB*CHUNK == N_EDGES exactly
#define P_SPLIT 8           // blocks per bucket in aggregation passes

__device__ __forceinline__ unsigned short f2bf(float x) {
    unsigned u = __float_as_uint(x);
    u += 0x7fffu + ((u >> 16) & 1u);      // RNE to bf16
    return (unsigned short)(u >> 16);
}
__device__ __forceinline__ float bf2f(unsigned short h) {
    return __uint_as_float((unsigned)h << 16);
}

// ---------------- fast path ----------------

// x_out = z0 ; zb = bf16(z0) for the ypass gather
__global__ __launch_bounds__(256) void prep_kernel(
    const float4* __restrict__ z, float4* __restrict__ x_out,
    ushort4* __restrict__ zb)
{
    int n = blockIdx.x * 256 + threadIdx.x;
    if (n >= N_NODES) return;
    float4 zv = z[n];
    x_out[n] = zv;
    ushort4 q;
    q.x = f2bf(zv.x); q.y = f2bf(zv.y); q.z = f2bf(zv.z); q.w = f2bf(zv.w);
    zb[n] = q;
}

// per-chunk bucket histogram, layout counts[sb*K + k]
__global__ __launch_bounds__(256) void hist_kernel(const int* __restrict__ dst,
                                                   int* __restrict__ counts)
{
    __shared__ int cnt[K_BUCKETS];
    int tid = threadIdx.x, sb = blockIdx.x;
    cnt[tid] = 0;
    __syncthreads();
    int e0 = sb * CHUNK;
    for (int i = tid; i < CHUNK; i += 256)
        atomicAdd(&cnt[dst[e0 + i] / BUCKET], 1);
    __syncthreads();
    counts[sb * K_BUCKETS + tid] = cnt[tid];
}

// per-bucket exclusive scan across chunks
__global__ __launch_bounds__(256) void scan_cols(const int* __restrict__ counts,
                                                 int* __restrict__ baseRel,
                                                 int* __restrict__ tot)
{
    __shared__ int buf[256];
    __shared__ int carry_s;
    int k = blockIdx.x, tid = threadIdx.x;
    if (tid == 0) carry_s = 0;
    __syncthreads();
    for (int base = 0; base < NSB; base += 256) {
        int idx = base + tid;
        int v = (idx < NSB) ? counts[idx * K_BUCKETS + k] : 0;
        buf[tid] = v;
        __syncthreads();
        for (int off = 1; off < 256; off <<= 1) {
            int t = (tid >= off) ? buf[tid - off] : 0;
            __syncthreads();
            buf[tid] += t;
            __syncthreads();
        }
        int incl = buf[tid];
        if (idx < NSB) baseRel[idx * K_BUCKETS + k] = carry_s + incl - v;
        __syncthreads();
        if (tid == 255) carry_s += incl;
        __syncthreads();
    }
    if (tid == 255) tot[k] = carry_s;
}

__global__ __launch_bounds__(256) void scan_tot(const int* __restrict__ tot,
                                                int* __restrict__ bstart)
{
    __shared__ int buf[256];
    int tid = threadIdx.x;
    int v = tot[tid];
    buf[tid] = v;
    __syncthreads();
    for (int off = 1; off < 256; off <<= 1) {
        int t = (tid >= off) ? buf[tid - off] : 0;
        __syncthreads();
        buf[tid] += t;
        __syncthreads();
    }
    bstart[tid] = buf[tid] - v;
    if (tid == 255) bstart[256] = buf[255];
}

// counting-sort scatter (round-7 proven): counts pre-loaded; permutation in LDS
__global__ __launch_bounds__(256) void scatter_kernel(
    const int* __restrict__ src, const int* __restrict__ dst,
    const float* __restrict__ r, const float* __restrict__ r_hat,
    const float* __restrict__ W, const float* __restrict__ b,
    const int* __restrict__ counts, const int* __restrict__ baseRel,
    const int* __restrict__ bstart,
    int* __restrict__ packedA, unsigned* __restrict__ c01a,
    unsigned short* __restrict__ c2a)
{
    __shared__ int cur[K_BUCKETS];
    __shared__ int delta[K_BUCKETS];
    __shared__ int scanbuf[256];
    __shared__ int            lpack[CHUNK];
    __shared__ unsigned       lc01[CHUNK];
    __shared__ unsigned short lc2[CHUNK];
    __shared__ unsigned char  skb[CHUNK];

    int tid = threadIdx.x, sb = blockIdx.x;

    int v = counts[sb * K_BUCKETS + tid];
    scanbuf[tid] = v;
    __syncthreads();
    for (int off = 1; off < 256; off <<= 1) {
        int t = (tid >= off) ? scanbuf[tid - off] : 0;
        __syncthreads();
        scanbuf[tid] += t;
        __syncthreads();
    }
    int localBase = scanbuf[tid] - v;
    int gBase = bstart[tid] + baseRel[sb * K_BUCKETS + tid];
    delta[tid] = gBase - localBase;
    cur[tid] = localBase;
    __syncthreads();

    float w8_0 = W[8],  w9_0 = W[9],  w10_0 = W[10], w11_0 = W[11], b0 = b[0];
    float w8_1 = W[20], w9_1 = W[21], w10_1 = W[22], w11_1 = W[23], b1 = b[1];
    float w8_2 = W[32], w9_2 = W[33], w10_2 = W[34], w11_2 = W[35], b2 = b[2];

    int e0 = sb * CHUNK;
    // pass B: coalesced global reads, scattered LDS writes to sorted slot
    for (int i = tid; i < CHUNK; i += 256) {
        int e = e0 + i;
        int d = dst[e];
        int k = d / BUCKET;
        int dl = d - k * BUCKET;
        int slot = atomicAdd(&cur[k], 1);
        int sn = src[e];
        float rv = r[e];
        size_t he = 3 * (size_t)e;
        float h0 = r_hat[he], h1 = r_hat[he + 1], h2 = r_hat[he + 2];
        lpack[slot] = (sn << 10) | dl;
        unsigned cc0 = f2bf(w8_0 * rv + w9_0 * h0 + w10_0 * h1 + w11_0 * h2 + b0);
        unsigned cc1 = f2bf(w8_1 * rv + w9_1 * h0 + w10_1 * h1 + w11_1 * h2 + b1);
        lc01[slot] = cc0 | (cc1 << 16);
        lc2[slot]  = f2bf(w8_2 * rv + w9_2 * h0 + w10_2 * h1 + w11_2 * h2 + b2);
        skb[slot]  = (unsigned char)k;
    }
    __syncthreads();

    // pass C: sequential LDS reads, coalesced global stores
    for (int s = tid; s < CHUNK; s += 256) {
        int k = skb[s];
        int gpos = delta[k] + s;
        packedA[gpos] = lpack[s];
        c01a[gpos] = lc01[s];
        c2a[gpos]  = lc2[s];
    }
}

// ONE static gather pass: g_i[n] = sum_{e->n} (a_i . z0[src] + c_i,e), deg[n]
__global__ __launch_bounds__(256) void ypass_kernel(
    const int* __restrict__ packedA, const unsigned* __restrict__ c01a,
    const unsigned short* __restrict__ c2a, const int* __restrict__ bstart,
    const ushort4* __restrict__ zb, const float* __restrict__ W,
    float4* __restrict__ gpart)
{
    __shared__ float g0sl[BUCKET], g1sl[BUCKET], g2sl[BUCKET], dgsl[BUCKET];
    int tid = threadIdx.x, blk = blockIdx.x;
    int k = blk / P_SPLIT;
    int p = blk - k * P_SPLIT;

    for (int i = tid; i < BUCKET; i += 256) {
        g0sl[i] = 0.f; g1sl[i] = 0.f; g2sl[i] = 0.f; dgsl[i] = 0.f;
    }
    __syncthreads();

    float a00 = W[0],  a01 = W[1],  a02 = W[2],  a03 = W[3];
    float a10 = W[12], a11 = W[13], a12 = W[14], a13 = W[15];
    float a20 = W[24], a21 = W[25], a22 = W[26], a23 = W[27];

    int estart = bstart[k], eend = bstart[k + 1];
    int len = eend - estart;
    int per = (len + P_SPLIT - 1) / P_SPLIT;
    int lo = estart + p * per;
    int hi = min(lo + per, eend);

    for (int j = lo + tid; j < hi; j += 256) {
        int pack = packedA[j];
        int s = pack >> 10;
        int dl = pack & 1023;
        ushort4 zq = zb[s];
        float z0v = bf2f(zq.x), z1v = bf2f(zq.y), z2v = bf2f(zq.z), z3v = bf2f(zq.w);
        unsigned cc = c01a[j];
        float c0 = bf2f((unsigned short)(cc & 0xffff));
        float c1 = bf2f((unsigned short)(cc >> 16));
        float c2 = bf2f(c2a[j]);
        atomicAdd(&g0sl[dl], a00*z0v + a01*z1v + a02*z2v + a03*z3v + c0);
        atomicAdd(&g1sl[dl], a10*z0v + a11*z1v + a12*z2v + a13*z3v + c1);
        atomicAdd(&g2sl[dl], a20*z0v + a21*z1v + a22*z2v + a23*z3v + c2);
        atomicAdd(&dgsl[dl], 1.0f);
    }
    __syncthreads();

    float4* pout = gpart + (size_t)blk * BUCKET;
    for (int i = tid; i < BUCKET; i += 256) {
        float4 o; o.x = g0sl[i]; o.y = g1sl[i]; o.z = g2sl[i]; o.w = dgsl[i];
        pout[i] = o;
    }
}

// finalize statics: g1,g2,deg arrays; S1 = g0 + deg*(q0 . z0)
__global__ __launch_bounds__(256) void fin0_kernel(
    const float4* __restrict__ gpart, const float4* __restrict__ z0,
    const float* __restrict__ W,
    float* __restrict__ g1, float* __restrict__ g2, float* __restrict__ deg,
    float* __restrict__ S1)
{
    int n = blockIdx.x * 256 + threadIdx.x;
    if (n >= N_NODES) return;
    int k = n / BUCKET;
    int i = n - k * BUCKET;
    const float4* pk = gpart + (size_t)k * P_SPLIT * BUCKET + i;
    float4 acc = pk[0];
#pragma unroll
    for (int p = 1; p < P_SPLIT; ++p) {
        float4 t = pk[(size_t)p * BUCKET];
        acc.x += t.x; acc.y += t.y; acc.z += t.z; acc.w += t.w;
    }
    g1[n] = acc.y; g2[n] = acc.z; deg[n] = acc.w;
    float q0 = W[4], q1 = W[5], q2 = W[6], q3 = W[7];
    float4 zv = z0[n];
    S1[n] = acc.x + acc.w * (q0*zv.x + q1*zv.y + q2*zv.z + q3*zv.w);
}

// per-layer scalar SpMV partials: t[n] = sum_{e->n} S[src_e]
__global__ __launch_bounds__(256) void spmv_kernel(
    const int* __restrict__ packedA, const int* __restrict__ bstart,
    const float* __restrict__ S, float* __restrict__ partial)
{
    __shared__ float tsl[BUCKET];
    int tid = threadIdx.x, blk = blockIdx.x;
    int k = blk / P_SPLIT;
    int p = blk - k * P_SPLIT;
    for (int i = tid; i < BUCKET; i += 256) tsl[i] = 0.f;
    __syncthreads();

    int estart = bstart[k], eend = bstart[k + 1];
    int len = eend - estart;
    int per = (len + P_SPLIT - 1) / P_SPLIT;
    int lo = estart + p * per;
    int hi = min(lo + per, eend);

    for (int j = lo + tid; j < hi; j += 256) {
        int pack = packedA[j];
        int s = pack >> 10;
        int dl = pack & 1023;
        atomicAdd(&tsl[dl], S[s]);
    }
    __syncthreads();
    float* pout = partial + (size_t)blk * BUCKET;
    for (int i = tid; i < BUCKET; i += 256) pout[i] = tsl[i];
}

// layer update (layers 1,2): S' = S + g_l + A_l*t + deg*(q_l . z0 + B_l*S)
template<int LAST>
__global__ __launch_bounds__(256) void finl_kernel(
    const float* __restrict__ partial, const float* __restrict__ gl,
    const float* __restrict__ deg, const float4* __restrict__ z0,
    const float* __restrict__ Sin, float* __restrict__ Sout,
    const float* __restrict__ W, int layer, float4* __restrict__ z_out)
{
    int n = blockIdx.x * 256 + threadIdx.x;
    if (n >= N_NODES) return;
    int k = n / BUCKET;
    int i = n - k * BUCKET;
    const float* pk = partial + (size_t)k * P_SPLIT * BUCKET + i;
    float t = 0.f;
#pragma unroll
    for (int p = 0; p < P_SPLIT; ++p) t += pk[(size_t)p * BUCKET];
    const float* Wl = W + 12 * layer;
    float a0 = Wl[0], a1 = Wl[1], a2 = Wl[2], a3 = Wl[3];
    float q0 = Wl[4], q1 = Wl[5], q2 = Wl[6], q3 = Wl[7];
    float A = a0 + a1 + a2 + a3, B = q0 + q1 + q2 + q3;
    float S = Sin[n];
    float4 zv = z0[n];
    float agg = gl[n] + A * t + deg[n] * (q0*zv.x + q1*zv.y + q2*zv.z + q3*zv.w + B * S);
    float Sn = S + agg;
    if (LAST) {
        float4 o = zv;
        o.x += Sn; o.y += Sn; o.z += Sn; o.w += Sn;
        z_out[n] = o;
    } else {
        Sout[n] = Sn;
    }
}

// ---------------- fallback (round-2) ----------------

__global__ __launch_bounds__(256) void init_kernel(
    const float4* __restrict__ z_in, float4* __restrict__ z_cur,
    float4* __restrict__ x_out, float* __restrict__ agg)
{
    int n = blockIdx.x * blockDim.x + threadIdx.x;
    if (n < N_NODES) {
        float4 vv = z_in[n];
        z_cur[n] = vv; x_out[n] = vv; agg[n] = 0.0f;
    }
}

__global__ __launch_bounds__(256) void edge_kernel(
    const float* __restrict__ z, const float* __restrict__ r,
    const float* __restrict__ r_hat, const int* __restrict__ src,
    const int* __restrict__ dst, const float* __restrict__ Wl,
    const float* __restrict__ bl, float* __restrict__ agg)
{
    int e = blockIdx.x * blockDim.x + threadIdx.x;
    if (e >= N_EDGES) return;
    float w0 = Wl[0], w1 = Wl[1], w2 = Wl[2], w3 = Wl[3];
    float w4 = Wl[4], w5 = Wl[5], w6 = Wl[6], w7 = Wl[7];
    float w8 = Wl[8], w9 = Wl[9], w10 = Wl[10], w11 = Wl[11];
    float bias = bl[0];
    int s = src[e], d = dst[e];
    float4 zs = ((const float4*)z)[s];
    float4 zd = ((const float4*)z)[d];
    float rv = r[e];
    const float* rh = r_hat + 3 * (size_t)e;
    float msg = w0*zs.x + w1*zs.y + w2*zs.z + w3*zs.w
              + w4*zd.x + w5*zd.y + w6*zd.z + w7*zd.w
              + w8*rv + w9*rh[0] + w10*rh[1] + w11*rh[2] + bias;
    unsafeAtomicAdd(&agg[d], msg);
}

__global__ __launch_bounds__(256) void node_update(float4* __restrict__ z_cur,
                                                   float* __restrict__ agg)
{
    int n = blockIdx.x * blockDim.x + threadIdx.x;
    if (n < N_NODES) {
        float a = agg[n]; float4 vv = z_cur[n];
        vv.x += a; vv.y += a; vv.z += a; vv.w += a;
        z_cur[n] = vv; agg[n] = 0.0f;
    }
}

__global__ __launch_bounds__(256) void final_update(const float4* __restrict__ z_cur,
                                                    const float* __restrict__ agg,
                                                    float4* __restrict__ z_out)
{
    int n = blockIdx.x * blockDim.x + threadIdx.x;
    if (n < N_NODES) {
        float a = agg[n]; float4 vv = z_cur[n];
        vv.x += a; vv.y += a; vv.z += a; vv.w += a;
        z_out[n] = vv;
    }
}

// ---------------- launch ----------------

extern "C" void kernel_launch(void* const* d_in, const int* in_sizes, int n_in,
                              void* d_out, int out_size, void* d_ws, size_t ws_size,
                              hipStream_t stream)
{
    const float* z     = (const float*)d_in[0];
    const float* r     = (const float*)d_in[1];
    const float* r_hat = (const float*)d_in[2];
    const float* W     = (const float*)d_in[3];
    const float* b     = (const float*)d_in[4];
    const int*   src   = (const int*)d_in[5];
    const int*   dst   = (const int*)d_in[6];
    float* out = (float*)d_out;

    char* ws = (char*)d_ws;
    size_t off = 0;
    auto alloc = [&](size_t bytes) {
        void* p = ws + off;
        off += (bytes + 15) & ~(size_t)15;
        return p;
    };
    int*            packedA = (int*)alloc((size_t)N_EDGES * 4);
    unsigned*       c01a    = (unsigned*)alloc((size_t)N_EDGES * 4);
    unsigned short* c2a     = (unsigned short*)alloc((size_t)N_EDGES * 2);
    int*            counts  = (int*)alloc((size_t)NSB * K_BUCKETS * 4);
    int*            baseRel = (int*)alloc((size_t)NSB * K_BUCKETS * 4);
    int*            tot     = (int*)alloc((size_t)K_BUCKETS * 4);
    int*            bstart  = (int*)alloc((size_t)(K_BUCKETS + 1) * 4);
    ushort4*        zb      = (ushort4*)alloc((size_t)N_NODES * 8);
    float4*         gpart   = (float4*)alloc((size_t)K_BUCKETS * P_SPLIT * BUCKET * 16);
    float*          g1      = (float*)alloc((size_t)N_NODES * 4);
    float*          g2      = (float*)alloc((size_t)N_NODES * 4);
    float*          deg     = (float*)alloc((size_t)N_NODES * 4);
    float*          Sa      = (float*)alloc((size_t)N_NODES * 4);
    float*          Sb      = (float*)alloc((size_t)N_NODES * 4);
    float*          pspmv   = (float*)alloc((size_t)K_BUCKETS * P_SPLIT * BUCKET * 4);
    size_t required = off;

    dim3 nblk((N_NODES + 255) / 256);

    if (ws_size >= required) {
        prep_kernel<<<nblk, 256, 0, stream>>>(
            (const float4*)z, (float4*)(out + 4 * (size_t)N_NODES), zb);
        hist_kernel<<<NSB, 256, 0, stream>>>(dst, counts);
        scan_cols<<<K_BUCKETS, 256, 0, stream>>>(counts, baseRel, tot);
        scan_tot<<<1, 256, 0, stream>>>(tot, bstart);
        scatter_kernel<<<NSB, 256, 0, stream>>>(src, dst, r, r_hat, W, b,
                                                counts, baseRel, bstart,
                                                packedA, c01a, c2a);
        // one static gather pass over edges
        ypass_kernel<<<K_BUCKETS * P_SPLIT, 256, 0, stream>>>(
            packedA, c01a, c2a, bstart, zb, W, gpart);
        fin0_kernel<<<nblk, 256, 0, stream>>>(
            gpart, (const float4*)z, W, g1, g2, deg, Sa);
        // layer 1: t1 = M . S1
        spmv_kernel<<<K_BUCKETS * P_SPLIT, 256, 0, stream>>>(packedA, bstart, Sa, pspmv);
        finl_kernel<0><<<nblk, 256, 0, stream>>>(
            pspmv, g1, deg, (const float4*)z, Sa, Sb, W, 1, (float4*)out);
        // layer 2: t2 = M . S2, write z_out
        spmv_kernel<<<K_BUCKETS * P_SPLIT, 256, 0, stream>>>(packedA, bstart, Sb, pspmv);
        finl_kernel<1><<<nblk, 256, 0, stream>>>(
            pspmv, g2, deg, (const float4*)z, Sb, Sa, W, 2, (float4*)out);
    } else {
        // fallback: round-2 path
        float* agg   = (float*)d_ws;
        float* z_cur = agg + N_NODES;
        dim3 eblk((N_EDGES + 255) / 256);
        init_kernel<<<nblk, 256, 0, stream>>>(
            (const float4*)z, (float4*)z_cur,
            (float4*)(out + 4 * (size_t)N_NODES), agg);
        for (int i = 0; i < 3; ++i) {
            edge_kernel<<<eblk, 256, 0, stream>>>(
                z_cur, r, r_hat, src, dst, W + 12 * i, b + i, agg);
            if (i < 2)
                node_update<<<nblk, 256, 0, stream>>>((float4*)z_cur, agg);
            else
                final_update<<<nblk, 256, 0, stream>>>(
                    (const float4*)z_cur, agg, (float4*)out);
        }
    }
}

// Round 11
// 430.383 us; speedup vs baseline: 1.1718x; 1.1510x over previous
//
#include <hip/hip_runtime.h>

#define N_NODES 200000
#define N_EDGES 6400000
#define K_BUCKETS 256
#define BUCKET 784          // 256*784 = 200704 >= 200000; dl < 1024
#define NSB 3200            // chunks
#define CHUNK 2000          // NSB*CHUNK == N_EDGES exactly
#define P_SPLIT 8           // blocks per bucket in gather passes

__device__ __forceinline__ unsigned short f2bf(float x) {
    unsigned u = __float_as_uint(x);
    u += 0x7fffu + ((u >> 16) & 1u);      // RNE to bf16
    return (unsigned short)(u >> 16);
}
__device__ __forceinline__ float bf2f(unsigned short h) {
    return __uint_as_float((unsigned)h << 16);
}

// ---------------- fast path ----------------

// x_out = z0 ; w0 = a0 . z0  (gather table for pass 1; S0 = 0)
__global__ __launch_bounds__(256) void prep_kernel(
    const float4* __restrict__ z, float4* __restrict__ x_out,
    const float* __restrict__ W, float* __restrict__ wtab)
{
    int n = blockIdx.x * 256 + threadIdx.x;
    if (n >= N_NODES) return;
    float4 zv = z[n];
    x_out[n] = zv;
    wtab[n] = W[0]*zv.x + W[1]*zv.y + W[2]*zv.z + W[3]*zv.w;
}

// per-chunk bucket histogram (int4-vectorized read; FIXED: loop covers all 500)
__global__ __launch_bounds__(256) void hist_kernel(const int* __restrict__ dst,
                                                   int* __restrict__ counts)
{
    __shared__ int cnt[K_BUCKETS];
    int tid = threadIdx.x, sb = blockIdx.x;
    cnt[tid] = 0;
    __syncthreads();
    int e0 = sb * CHUNK;
    const int4* d4p = (const int4*)(dst + e0);
    for (int i4 = tid; i4 < CHUNK / 4; i4 += 256) {   // 500 int4s = 2000 edges
        int4 d4 = d4p[i4];
        atomicAdd(&cnt[d4.x / BUCKET], 1);
        atomicAdd(&cnt[d4.y / BUCKET], 1);
        atomicAdd(&cnt[d4.z / BUCKET], 1);
        atomicAdd(&cnt[d4.w / BUCKET], 1);
    }
    __syncthreads();
    counts[sb * K_BUCKETS + tid] = cnt[tid];
}

// per-bucket exclusive scan across chunks
__global__ __launch_bounds__(256) void scan_cols(const int* __restrict__ counts,
                                                 int* __restrict__ baseRel,
                                                 int* __restrict__ tot)
{
    __shared__ int buf[256];
    __shared__ int carry_s;
    int k = blockIdx.x, tid = threadIdx.x;
    if (tid == 0) carry_s = 0;
    __syncthreads();
    for (int base = 0; base < NSB; base += 256) {
        int idx = base + tid;
        int v = (idx < NSB) ? counts[idx * K_BUCKETS + k] : 0;
        buf[tid] = v;
        __syncthreads();
        for (int off = 1; off < 256; off <<= 1) {
            int t = (tid >= off) ? buf[tid - off] : 0;
            __syncthreads();
            buf[tid] += t;
            __syncthreads();
        }
        int incl = buf[tid];
        if (idx < NSB) baseRel[idx * K_BUCKETS + k] = carry_s + incl - v;
        __syncthreads();
        if (tid == 255) carry_s += incl;
        __syncthreads();
    }
    if (tid == 255) tot[k] = carry_s;
}

__global__ __launch_bounds__(256) void scan_tot(const int* __restrict__ tot,
                                                int* __restrict__ bstart)
{
    __shared__ int buf[256];
    int tid = threadIdx.x;
    int v = tot[tid];
    buf[tid] = v;
    __syncthreads();
    for (int off = 1; off < 256; off <<= 1) {
        int t = (tid >= off) ? buf[tid - off] : 0;
        __syncthreads();
        buf[tid] += t;
        __syncthreads();
    }
    bstart[tid] = buf[tid] - v;
    if (tid == 255) bstart[256] = buf[255];
}

// counting-sort scatter: counts pre-loaded; permutation in LDS; unroll-2 loads
__global__ __launch_bounds__(256) void scatter_kernel(
    const int* __restrict__ src, const int* __restrict__ dst,
    const float* __restrict__ r, const float* __restrict__ r_hat,
    const float* __restrict__ W, const float* __restrict__ b,
    const int* __restrict__ counts, const int* __restrict__ baseRel,
    const int* __restrict__ bstart,
    int* __restrict__ packedA,
    unsigned short* __restrict__ c0a, unsigned short* __restrict__ c1a,
    unsigned short* __restrict__ c2a)
{
    __shared__ int cur[K_BUCKETS];
    __shared__ int delta[K_BUCKETS];
    __shared__ int scanbuf[256];
    __shared__ int            lpack[CHUNK];
    __shared__ unsigned short lc0[CHUNK];
    __shared__ unsigned short lc1[CHUNK];
    __shared__ unsigned short lc2[CHUNK];
    __shared__ unsigned char  skb[CHUNK];

    int tid = threadIdx.x, sb = blockIdx.x;

    int v = counts[sb * K_BUCKETS + tid];
    scanbuf[tid] = v;
    __syncthreads();
    for (int off = 1; off < 256; off <<= 1) {
        int t = (tid >= off) ? scanbuf[tid - off] : 0;
        __syncthreads();
        scanbuf[tid] += t;
        __syncthreads();
    }
    int localBase = scanbuf[tid] - v;
    int gBase = bstart[tid] + baseRel[sb * K_BUCKETS + tid];
    delta[tid] = gBase - localBase;
    cur[tid] = localBase;
    __syncthreads();

    float w8_0 = W[8],  w9_0 = W[9],  w10_0 = W[10], w11_0 = W[11], b0 = b[0];
    float w8_1 = W[20], w9_1 = W[21], w10_1 = W[22], w11_1 = W[23], b1 = b[1];
    float w8_2 = W[32], w9_2 = W[33], w10_2 = W[34], w11_2 = W[35], b2 = b[2];

    int e0 = sb * CHUNK;
    int i = tid;
    // unroll-2: batch the global loads of two edges for MLP
    for (; i + 256 < CHUNK; i += 512) {
        int ea = e0 + i, eb = e0 + i + 256;
        int da = dst[ea], db = dst[eb];
        int sa = src[ea], sb2 = src[eb];
        float ra = r[ea], rb = r[eb];
        size_t ha = 3 * (size_t)ea, hb = 3 * (size_t)eb;
        float a0h = r_hat[ha], a1h = r_hat[ha+1], a2h = r_hat[ha+2];
        float b0h = r_hat[hb], b1h = r_hat[hb+1], b2h = r_hat[hb+2];

        int ka = da / BUCKET, dla = da - ka * BUCKET;
        int slota = atomicAdd(&cur[ka], 1);
        lpack[slota] = (sa << 10) | dla;
        lc0[slota] = f2bf(w8_0*ra + w9_0*a0h + w10_0*a1h + w11_0*a2h + b0);
        lc1[slota] = f2bf(w8_1*ra + w9_1*a0h + w10_1*a1h + w11_1*a2h + b1);
        lc2[slota] = f2bf(w8_2*ra + w9_2*a0h + w10_2*a1h + w11_2*a2h + b2);
        skb[slota] = (unsigned char)ka;

        int kb = db / BUCKET, dlb = db - kb * BUCKET;
        int slotb = atomicAdd(&cur[kb], 1);
        lpack[slotb] = (sb2 << 10) | dlb;
        lc0[slotb] = f2bf(w8_0*rb + w9_0*b0h + w10_0*b1h + w11_0*b2h + b0);
        lc1[slotb] = f2bf(w8_1*rb + w9_1*b0h + w10_1*b1h + w11_1*b2h + b1);
        lc2[slotb] = f2bf(w8_2*rb + w9_2*b0h + w10_2*b1h + w11_2*b2h + b2);
        skb[slotb] = (unsigned char)kb;
    }
    for (; i < CHUNK; i += 256) {
        int e = e0 + i;
        int d = dst[e];
        int k = d / BUCKET;
        int dl = d - k * BUCKET;
        int slot = atomicAdd(&cur[k], 1);
        int sn = src[e];
        float rv = r[e];
        size_t he = 3 * (size_t)e;
        float h0 = r_hat[he], h1 = r_hat[he+1], h2 = r_hat[he+2];
        lpack[slot] = (sn << 10) | dl;
        lc0[slot] = f2bf(w8_0*rv + w9_0*h0 + w10_0*h1 + w11_0*h2 + b0);
        lc1[slot] = f2bf(w8_1*rv + w9_1*h0 + w10_1*h1 + w11_1*h2 + b1);
        lc2[slot] = f2bf(w8_2*rv + w9_2*h0 + w10_2*h1 + w11_2*h2 + b2);
        skb[slot] = (unsigned char)k;
    }
    __syncthreads();

    for (int s = tid; s < CHUNK; s += 256) {
        int k = skb[s];
        int gpos = delta[k] + s;
        packedA[gpos] = lpack[s];
        c0a[gpos] = lc0[s];
        c1a[gpos] = lc1[s];
        c2a[gpos] = lc2[s];
    }
}

// gather pass: G[n] = sum_{e->n} (wtab[src] + c_e); FIRST also accumulates deg.
// unroll-4 with batched loads -> 4 independent gathers in flight.
template<int FIRST>
__global__ __launch_bounds__(256) void gpass_kernel(
    const int* __restrict__ packedA, const unsigned short* __restrict__ cb,
    const int* __restrict__ bstart, const float* __restrict__ wtab,
    float* __restrict__ gpart, float* __restrict__ dpart)
{
    __shared__ float gsl[BUCKET];
    __shared__ float dsl[FIRST ? BUCKET : 1];
    int tid = threadIdx.x, blk = blockIdx.x;
    int k = blk / P_SPLIT;
    int p = blk - k * P_SPLIT;

    for (int i = tid; i < BUCKET; i += 256) {
        gsl[i] = 0.0f;
        if (FIRST) dsl[i] = 0.0f;
    }
    __syncthreads();

    int estart = bstart[k], eend = bstart[k + 1];
    int len = eend - estart;
    int per = (len + P_SPLIT - 1) / P_SPLIT;
    int lo = estart + p * per;
    int hi = min(lo + per, eend);

    int j = lo + tid;
    for (; j + 768 < hi; j += 1024) {
        int p0 = packedA[j];
        int p1 = packedA[j + 256];
        int p2 = packedA[j + 512];
        int p3 = packedA[j + 768];
        unsigned short q0 = cb[j], q1 = cb[j + 256], q2 = cb[j + 512], q3 = cb[j + 768];
        float g0 = wtab[p0 >> 10];
        float g1 = wtab[p1 >> 10];
        float g2 = wtab[p2 >> 10];
        float g3 = wtab[p3 >> 10];
        atomicAdd(&gsl[p0 & 1023], g0 + bf2f(q0));
        atomicAdd(&gsl[p1 & 1023], g1 + bf2f(q1));
        atomicAdd(&gsl[p2 & 1023], g2 + bf2f(q2));
        atomicAdd(&gsl[p3 & 1023], g3 + bf2f(q3));
        if (FIRST) {
            atomicAdd(&dsl[p0 & 1023], 1.0f);
            atomicAdd(&dsl[p1 & 1023], 1.0f);
            atomicAdd(&dsl[p2 & 1023], 1.0f);
            atomicAdd(&dsl[p3 & 1023], 1.0f);
        }
    }
    for (; j < hi; j += 256) {
        int pk = packedA[j];
        atomicAdd(&gsl[pk & 1023], wtab[pk >> 10] + bf2f(cb[j]));
        if (FIRST) atomicAdd(&dsl[pk & 1023], 1.0f);
    }
    __syncthreads();

    float* gout = gpart + (size_t)blk * BUCKET;
    for (int i = tid; i < BUCKET; i += 256) {
        gout[i] = gsl[i];
        if (FIRST) dpart[(size_t)blk * BUCKET + i] = dsl[i];
    }
}

// finalize layer: S' = S + G + deg*(q.z0 + B*S); emit next wtab or z_out
__global__ __launch_bounds__(256) void fin_kernel(
    const float* __restrict__ gpart, const float* __restrict__ dpart,
    const float4* __restrict__ z0, const float* __restrict__ Sin,
    float* __restrict__ Sout, float* __restrict__ deg,
    const float* __restrict__ W, int layer, float* __restrict__ wnext,
    float4* __restrict__ z_out)
{
    int n = blockIdx.x * 256 + threadIdx.x;
    if (n >= N_NODES) return;
    int k = n / BUCKET;
    int i = n - k * BUCKET;
    const float* gk = gpart + (size_t)k * P_SPLIT * BUCKET + i;
    float G = 0.0f;
#pragma unroll
    for (int p = 0; p < P_SPLIT; ++p) G += gk[(size_t)p * BUCKET];

    float dg;
    if (layer == 0) {
        const float* dk = dpart + (size_t)k * P_SPLIT * BUCKET + i;
        dg = 0.0f;
#pragma unroll
        for (int p = 0; p < P_SPLIT; ++p) dg += dk[(size_t)p * BUCKET];
        deg[n] = dg;
    } else {
        dg = deg[n];
    }

    const float* Wl = W + 12 * layer;
    float q0 = Wl[4], q1 = Wl[5], q2 = Wl[6], q3 = Wl[7];
    float B = q0 + q1 + q2 + q3;
    float4 zv = z0[n];
    float S = (layer == 0) ? 0.0f : Sin[n];
    float Sn = S + G + dg * (q0*zv.x + q1*zv.y + q2*zv.z + q3*zv.w + B * S);

    if (layer < 2) {
        Sout[n] = Sn;
        const float* Wn = W + 12 * (layer + 1);
        float a0 = Wn[0], a1 = Wn[1], a2 = Wn[2], a3 = Wn[3];
        float A = a0 + a1 + a2 + a3;
        wnext[n] = a0*zv.x + a1*zv.y + a2*zv.z + a3*zv.w + A * Sn;
    } else {
        float4 o = zv;
        o.x += Sn; o.y += Sn; o.z += Sn; o.w += Sn;
        z_out[n] = o;
    }
}

// ---------------- fallback (round-2) ----------------

__global__ __launch_bounds__(256) void init_kernel(
    const float4* __restrict__ z_in, float4* __restrict__ z_cur,
    float4* __restrict__ x_out, float* __restrict__ agg)
{
    int n = blockIdx.x * blockDim.x + threadIdx.x;
    if (n < N_NODES) {
        float4 vv = z_in[n];
        z_cur[n] = vv; x_out[n] = vv; agg[n] = 0.0f;
    }
}

__global__ __launch_bounds__(256) void edge_kernel(
    const float* __restrict__ z, const float* __restrict__ r,
    const float* __restrict__ r_hat, const int* __restrict__ src,
    const int* __restrict__ dst, const float* __restrict__ Wl,
    const float* __restrict__ bl, float* __restrict__ agg)
{
    int e = blockIdx.x * blockDim.x + threadIdx.x;
    if (e >= N_EDGES) return;
    float w0 = Wl[0], w1 = Wl[1], w2 = Wl[2], w3 = Wl[3];
    float w4 = Wl[4], w5 = Wl[5], w6 = Wl[6], w7 = Wl[7];
    float w8 = Wl[8], w9 = Wl[9], w10 = Wl[10], w11 = Wl[11];
    float bias = bl[0];
    int s = src[e], d = dst[e];
    float4 zs = ((const float4*)z)[s];
    float4 zd = ((const float4*)z)[d];
    float rv = r[e];
    const float* rh = r_hat + 3 * (size_t)e;
    float msg = w0*zs.x + w1*zs.y + w2*zs.z + w3*zs.w
              + w4*zd.x + w5*zd.y + w6*zd.z + w7*zd.w
              + w8*rv + w9*rh[0] + w10*rh[1] + w11*rh[2] + bias;
    unsafeAtomicAdd(&agg[d], msg);
}

__global__ __launch_bounds__(256) void node_update(float4* __restrict__ z_cur,
                                                   float* __restrict__ agg)
{
    int n = blockIdx.x * blockDim.x + threadIdx.x;
    if (n < N_NODES) {
        float a = agg[n]; float4 vv = z_cur[n];
        vv.x += a; vv.y += a; vv.z += a; vv.w += a;
        z_cur[n] = vv; agg[n] = 0.0f;
    }
}

__global__ __launch_bounds__(256) void final_update(const float4* __restrict__ z_cur,
                                                    const float* __restrict__ agg,
                                                    float4* __restrict__ z_out)
{
    int n = blockIdx.x * blockDim.x + threadIdx.x;
    if (n < N_NODES) {
        float a = agg[n]; float4 vv = z_cur[n];
        vv.x += a; vv.y += a; vv.z += a; vv.w += a;
        z_out[n] = vv;
    }
}

// ---------------- launch ----------------

extern "C" void kernel_launch(void* const* d_in, const int* in_sizes, int n_in,
                              void* d_out, int out_size, void* d_ws, size_t ws_size,
                              hipStream_t stream)
{
    const float* z     = (const float*)d_in[0];
    const float* r     = (const float*)d_in[1];
    const float* r_hat = (const float*)d_in[2];
    const float* W     = (const float*)d_in[3];
    const float* b     = (const float*)d_in[4];
    const int*   src   = (const int*)d_in[5];
    const int*   dst   = (const int*)d_in[6];
    float* out = (float*)d_out;

    char* ws = (char*)d_ws;
    size_t off = 0;
    auto alloc = [&](size_t bytes) {
        void* p = ws + off;
        off += (bytes + 15) & ~(size_t)15;
        return p;
    };
    int*            packedA = (int*)alloc((size_t)N_EDGES * 4);
    unsigned short* c0a     = (unsigned short*)alloc((size_t)N_EDGES * 2);
    unsigned short* c1a     = (unsigned short*)alloc((size_t)N_EDGES * 2);
    unsigned short* c2a     = (unsigned short*)alloc((size_t)N_EDGES * 2);
    int*            counts  = (int*)alloc((size_t)NSB * K_BUCKETS * 4);
    int*            baseRel = (int*)alloc((size_t)NSB * K_BUCKETS * 4);
    int*            tot     = (int*)alloc((size_t)K_BUCKETS * 4);
    int*            bstart  = (int*)alloc((size_t)(K_BUCKETS + 1) * 4);
    float*          wtab    = (float*)alloc((size_t)N_NODES * 4);
    float*          Sa      = (float*)alloc((size_t)N_NODES * 4);
    float*          Sb      = (float*)alloc((size_t)N_NODES * 4);
    float*          deg     = (float*)alloc((size_t)N_NODES * 4);
    float*          gpart   = (float*)alloc((size_t)K_BUCKETS * P_SPLIT * BUCKET * 4);
    float*          dpart   = (float*)alloc((size_t)K_BUCKETS * P_SPLIT * BUCKET * 4);
    size_t required = off;

    dim3 nblk((N_NODES + 255) / 256);

    if (ws_size >= required) {
        prep_kernel<<<nblk, 256, 0, stream>>>(
            (const float4*)z, (float4*)(out + 4 * (size_t)N_NODES), W, wtab);
        hist_kernel<<<NSB, 256, 0, stream>>>(dst, counts);
        scan_cols<<<K_BUCKETS, 256, 0, stream>>>(counts, baseRel, tot);
        scan_tot<<<1, 256, 0, stream>>>(tot, bstart);
        scatter_kernel<<<NSB, 256, 0, stream>>>(src, dst, r, r_hat, W, b,
                                                counts, baseRel, bstart,
                                                packedA, c0a, c1a, c2a);
        // layer 0: G0 + deg
        gpass_kernel<1><<<K_BUCKETS * P_SPLIT, 256, 0, stream>>>(
            packedA, c0a, bstart, wtab, gpart, dpart);
        fin_kernel<<<nblk, 256, 0, stream>>>(
            gpart, dpart, (const float4*)z, Sa, Sa, deg, W, 0, wtab, (float4*)out);
        // layer 1: G1
        gpass_kernel<0><<<K_BUCKETS * P_SPLIT, 256, 0, stream>>>(
            packedA, c1a, bstart, wtab, gpart, dpart);
        fin_kernel<<<nblk, 256, 0, stream>>>(
            gpart, dpart, (const float4*)z, Sa, Sb, deg, W, 1, wtab, (float4*)out);
        // layer 2: G2 -> z_out
        gpass_kernel<0><<<K_BUCKETS * P_SPLIT, 256, 0, stream>>>(
            packedA, c2a, bstart, wtab, gpart, dpart);
        fin_kernel<<<nblk, 256, 0, stream>>>(
            gpart, dpart, (const float4*)z, Sb, Sa, deg, W, 2, wtab, (float4*)out);
    } else {
        // fallback: round-2 path
        float* agg   = (float*)d_ws;
        float* z_cur = agg + N_NODES;
        dim3 eblk((N_EDGES + 255) / 256);
        init_kernel<<<nblk, 256, 0, stream>>>(
            (const float4*)z, (float4*)z_cur,
            (float4*)(out + 4 * (size_t)N_NODES), agg);
        for (int i = 0; i < 3; ++i) {
            edge_kernel<<<eblk, 256, 0, stream>>>(
                z_cur, r, r_hat, src, dst, W + 12 * i, b + i, agg);
            if (i < 2)
                node_update<<<nblk, 256, 0, stream>>>((float4*)z_cur, agg);
            else
                final_update<<<nblk, 256, 0, stream>>>(
                    (const float4*)z_cur, agg, (float4*)out);
        }
    }
}